// Round 7
// baseline (355.747 us; speedup 1.0000x reference)
//
#include <hip/hip_runtime.h>
#include <math.h>

#define B_ 4
#define C_ 512
#define N_ 4096
#define LOG2E 1.44269504088896f

typedef __attribute__((ext_vector_type(8))) short s8v;   // 8 bf16
typedef __attribute__((ext_vector_type(4))) float f4v;   // MFMA acc

#define MF32(a, b, c) __builtin_amdgcn_mfma_f32_16x16x32_bf16(a, b, c, 0, 0, 0)

#if defined(__has_builtin) && __has_builtin(__builtin_amdgcn_exp2f)
#define EXP2(x) __builtin_amdgcn_exp2f(x)
#else
#define EXP2(x) exp2f(x)
#endif

// Raw barrier: drains LDS ops only (cross-wave P visibility); global-load
// prefetches stay IN FLIGHT across the barrier.
#define BARRIER_LDS() do {                                   \
    __builtin_amdgcn_sched_barrier(0);                       \
    asm volatile("s_waitcnt lgkmcnt(0)" ::: "memory");       \
    __builtin_amdgcn_s_barrier();                            \
    __builtin_amdgcn_sched_barrier(0);                       \
} while (0)

static __device__ __forceinline__ ushort f2bf(float f) {   // RNE
    unsigned u = __float_as_uint(f);
    u += 0x7FFFu + ((u >> 16) & 1u);
    return (ushort)(u >> 16);
}
static __device__ __forceinline__ unsigned pack2bf(float a, float b) {
    unsigned ua = __float_as_uint(a); ua += 0x7FFFu + ((ua >> 16) & 1u);
    unsigned ub = __float_as_uint(b); ub += 0x7FFFu + ((ub >> 16) & 1u);
    return (ua >> 16) | (ub & 0xffff0000u);
}

// ---------------------------------------------------------------------------
// Pass A: Wq|Wk|Wv -> Wb [640][512] bf16
// ---------------------------------------------------------------------------
__global__ __launch_bounds__(256) void wconv_kernel(
    const float* __restrict__ Wq, const float* __restrict__ Wk,
    const float* __restrict__ Wv, ushort* __restrict__ Wb)
{
    const int row = blockIdx.x;
    const float* src = row < 64 ? Wq + (size_t)row * C_
                     : row < 128 ? Wk + (size_t)(row - 64) * C_
                     : Wv + (size_t)(row - 128) * C_;
    const int t2 = threadIdx.x * 2;
    float2 v = *(const float2*)&src[t2];
    ushort2 o; o.x = f2bf(v.x); o.y = f2bf(v.y);
    *(ushort2*)&Wb[(size_t)row * C_ + t2] = o;
}

// ---------------------------------------------------------------------------
// Pass B: fused QKV (unchanged from R4).
// grid (N/64, B) = 256 blocks (1/CU), block 512 (8 waves). Xs [64][512]
// XOR-swizzled, Wb register prefetch 1 k-iter ahead.
// ---------------------------------------------------------------------------
__global__ __launch_bounds__(512, 2) void qkv_fused(
    const float* __restrict__ x, const ushort* __restrict__ Wb,
    const float* __restrict__ bq, const float* __restrict__ bk,
    const float* __restrict__ bv,
    ushort* __restrict__ qT, ushort* __restrict__ kT, ushort* __restrict__ vB)
{
    extern __shared__ ushort Xs[];   // [64][512] bf16, XOR-swizzled, 64 KB

    const int tid = threadIdx.x, w = tid >> 6, lane = tid & 63;
    const int li = lane & 15, qd = lane >> 4;
    const int n0 = blockIdx.x * 64, b = blockIdx.y;

    // ---- stage x[c][n0..n0+63] -> Xs[n][c] bf16 (swizzled) ----
    #pragma unroll
    for (int r = 0; r < 16; ++r) {
        const int f = r * 512 + tid;
        const int c = f >> 4;          // 0..511
        const int nch = f & 15;        // 4-float chunk in n
        float4 v = *(const float4*)&x[((size_t)b * C_ + c) * N_ + n0 + nch * 4];
        const int n = nch * 4;
        Xs[((n + 0) * 512 + c) ^ (((n + 0) & 7) << 3)] = f2bf(v.x);
        Xs[((n + 1) * 512 + c) ^ (((n + 1) & 7) << 3)] = f2bf(v.y);
        Xs[((n + 2) * 512 + c) ^ (((n + 2) & 7) << 3)] = f2bf(v.z);
        Xs[((n + 3) * 512 + c) ^ (((n + 3) & 7) << 3)] = f2bf(v.w);
    }
    __syncthreads();

    const int rb0 = w * 80;
    const ushort* wrow[5];
    #pragma unroll
    for (int ot = 0; ot < 5; ++ot)
        wrow[ot] = Wb + (size_t)(rb0 + ot * 16 + li) * C_ + qd * 8;

    f4v acc[5][4];
    #pragma unroll
    for (int ot = 0; ot < 5; ++ot)
        #pragma unroll
        for (int nt = 0; nt < 4; ++nt)
            acc[ot][nt] = (f4v){0.f, 0.f, 0.f, 0.f};

    // Wb rolling register prefetch (distance 1 k-iter)
    s8v awc[5], awn[5];
    #pragma unroll
    for (int ot = 0; ot < 5; ++ot)
        awc[ot] = *(const s8v*)(wrow[ot]);

    #pragma unroll 1
    for (int kc = 0; kc < C_; kc += 32) {
        const int kn = (kc + 32 < C_) ? kc + 32 : 0;   // last prefetch harmless
        #pragma unroll
        for (int ot = 0; ot < 5; ++ot)
            awn[ot] = *(const s8v*)(wrow[ot] + kn);

        s8v bx[4];
        #pragma unroll
        for (int nt = 0; nt < 4; ++nt) {
            const int n = nt * 16 + li;                // n&7 == li&7
            bx[nt] = *(const s8v*)&Xs[((n * 512) + kc + qd * 8) ^ ((li & 7) << 3)];
        }

        #pragma unroll
        for (int ot = 0; ot < 5; ++ot) {
            if (rb0 + ot * 16 >= 128) {       // v: swapped -> D[m=n][col=o]
                #pragma unroll
                for (int nt = 0; nt < 4; ++nt)
                    acc[ot][nt] = MF32(bx[nt], awc[ot], acc[ot][nt]);
            } else {                           // q/k: D[m=o][col=n]
                #pragma unroll
                for (int nt = 0; nt < 4; ++nt)
                    acc[ot][nt] = MF32(awc[ot], bx[nt], acc[ot][nt]);
            }
        }
        #pragma unroll
        for (int ot = 0; ot < 5; ++ot) awc[ot] = awn[ot];
    }

    #pragma unroll
    for (int ot = 0; ot < 5; ++ot) {
        const int rb = rb0 + ot * 16;
        if (rb < 128) {   // q or k: lane col = n, rows = o (qd*4+r)
            ushort* dst = rb < 64 ? qT : kT;
            const float* bias = rb < 64 ? bq : bk;
            const int ob = (rb < 64 ? rb : rb - 64) + qd * 4;
            const float sc = rb < 64 ? LOG2E : 1.0f;
            #pragma unroll
            for (int nt = 0; nt < 4; ++nt) {
                const int n = n0 + nt * 16 + li;
                ushort4 o;
                o.x = f2bf((acc[ot][nt][0] + bias[ob + 0]) * sc);
                o.y = f2bf((acc[ot][nt][1] + bias[ob + 1]) * sc);
                o.z = f2bf((acc[ot][nt][2] + bias[ob + 2]) * sc);
                o.w = f2bf((acc[ot][nt][3] + bias[ob + 3]) * sc);
                *(ushort4*)&dst[((size_t)b * N_ + n) * 64 + ob] = o;
            }
        } else {          // v: lane col = o (c), rows = n
            const int c = rb - 128 + li;
            const float bb = bv[c];
            #pragma unroll
            for (int nt = 0; nt < 4; ++nt) {
                const int n = n0 + nt * 16 + qd * 4;
                ushort4 o;
                o.x = f2bf(acc[ot][nt][0] + bb);
                o.y = f2bf(acc[ot][nt][1] + bb);
                o.z = f2bf(acc[ot][nt][2] + bb);
                o.w = f2bf(acc[ot][nt][3] + bb);
                *(ushort4*)&vB[((size_t)b * C_ + c) * N_ + n] = o;
            }
        }
    }
}

// ---------------------------------------------------------------------------
// Pass C: MFMA flash attention, producer/consumer waves (R7).
// Grid 256 blocks (1/CU, XCD-pinned via wg&7), block 768 = 12 waves.
// Waves 0-7  (S-producers, j=16 each): S(t) = K^T Q, exp2, pack -> Pw, l.
// Waves 8-11 (PV-consumers, c=64 EACH): read Pr ONCE, reuse each pf
//   fragment across 4 ct (was 2) -> total P LDS reads per iter HALVED
//   (256 -> 128 ds_read_b128/CU). LDS pipe was ~40-50% of the 8000-cyc
//   iteration (each of 8 consumer waves re-read the full 32KB P tile).
// Per SIMD: 2 S-waves + 1 PV-wave; MFMA total unchanged (160/SIMD/iter).
// P ping-pong [128][128] XOR-16B-chunk swizzled; LDS 69632 B.
// ---------------------------------------------------------------------------
__device__ __forceinline__ void pv_chunk(
    const ushort* __restrict__ Pr, int li, int qd, int cidx,
    const s8v* vf, f4v (&acc)[4][8])
{
    const int sw = li & 7;             // == row&7 for all rows this lane reads
    #pragma unroll
    for (int h = 0; h < 2; ++h) {          // halves keep pf live-range at 4
        s8v pf[4];
        #pragma unroll
        for (int g = 0; g < 4; ++g)
            pf[g] = *(const s8v*)&Pr[(size_t)((h * 4 + g) * 16 + li) * 128
                                     + (((cidx * 4 + qd) ^ sw) << 3)];
        #pragma unroll
        for (int ct = 0; ct < 4; ++ct)
            #pragma unroll
            for (int g = 0; g < 4; ++g)
                acc[ct][h * 4 + g] = MF32(vf[ct], pf[g], acc[ct][h * 4 + g]);
    }
}

__device__ __forceinline__ void s_phase(
    s8v ck0, s8v ck1, const s8v (&qf)[8][2], float (&lp)[8],
    ushort* __restrict__ Pw, int li, int qd, int w2)
{
    const int chunk = w2 * 2 + (qd >> 1);  // 16B chunk of logical col
    const int off = (qd & 1) * 4;          // 8B offset within chunk (shorts)
    const int sw = li & 7;                 // == row&7
    #pragma unroll
    for (int h = 0; h < 2; ++h) {          // halves keep sac live-range at 4
        f4v sac[4];
        #pragma unroll
        for (int g = 0; g < 4; ++g) {
            const int it = h * 4 + g;
            sac[g] = (f4v){0.f, 0.f, 0.f, 0.f};
            sac[g] = MF32(ck0, qf[it][0], sac[g]);
            sac[g] = MF32(ck1, qf[it][1], sac[g]);
        }
        #pragma unroll
        for (int g = 0; g < 4; ++g) {
            const int it = h * 4 + g;
            const float p0 = EXP2(sac[g][0]);
            const float p1 = EXP2(sac[g][1]);
            const float p2 = EXP2(sac[g][2]);
            const float p3 = EXP2(sac[g][3]);
            lp[it] += (p0 + p1) + (p2 + p3);
            uint2 u; u.x = pack2bf(p0, p1); u.y = pack2bf(p2, p3);
            *(uint2*)&Pw[(size_t)(it * 16 + li) * 128
                         + ((chunk ^ sw) << 3) + off] = u;
        }
    }
}

__global__ __launch_bounds__(768) void attn_mfma(
    const ushort* __restrict__ qT, const ushort* __restrict__ kT,
    const ushort* __restrict__ vB, const float* __restrict__ x,
    const float* __restrict__ gamma, float* __restrict__ out)
{
    extern __shared__ char smem[];
    ushort* Pb0 = (ushort*)smem;               // [128][128] swizzled
    ushort* Pb1 = (ushort*)(smem + 32768);     // [128][128] swizzled
    float*  l_s = (float*)(smem + 65536);      // [8][128]

    const int tid = threadIdx.x, w = tid >> 6, lane = tid & 63;
    const int li = lane & 15, qd = lane >> 4;
    // XCD grouping (R5): wg -> XCD = wg%8; all 32 i-tiles of one (b, c_half)
    // combo land on one XCD -> V/K/Q L2-resident per XCD (verified: FETCH 3.2x down).
    const int wg = blockIdx.x;
    const int i_base = (wg >> 3) * 128;
    const int combo = wg & 7;
    const int b = combo >> 1;
    const int c_base = (combo & 1) * 256;

    const ushort* qTb = qT + (size_t)b * N_ * 64;
    const ushort* kTb = kT + (size_t)b * N_ * 64;
    const ushort* vBb = vB + (size_t)b * C_ * N_;

    if (w < 8) {
        // =============== S-producer waves ===============
        const int w2 = w;
        s8v qf[8][2];
        #pragma unroll
        for (int it = 0; it < 8; ++it)
            #pragma unroll
            for (int ks = 0; ks < 2; ++ks)
                qf[it][ks] = *(const s8v*)&qTb[(size_t)(i_base + it * 16 + li) * 64 + ks * 32 + qd * 8];
        float lp[8] = {0.f, 0.f, 0.f, 0.f, 0.f, 0.f, 0.f, 0.f};

        const ushort* kptr = kTb + (size_t)(w2 * 16 + li) * 64 + qd * 8;

        // interval 0: K(0), S(0)->Pb0, prefetch K(1)
        s8v kc0 = *(const s8v*)(kptr);
        s8v kc1 = *(const s8v*)(kptr + 32);
        s8v kn0 = *(const s8v*)(kptr + (size_t)128 * 64);
        s8v kn1 = *(const s8v*)(kptr + (size_t)128 * 64 + 32);
        s_phase(kc0, kc1, qf, lp, Pb0, li, qd, w2);
        BARRIER_LDS();                                   // #1

        #pragma unroll 1
        for (int t = 1; t < N_ / 128; ++t) {
            ushort* Pw = ((t - 1) & 1) ? Pb0 : Pb1;
            const size_t jnext = (t + 1 < N_ / 128) ? (size_t)(t + 1) * 128 : 0;
            s8v ck0 = kn0, ck1 = kn1;
            kn0 = *(const s8v*)(kptr + jnext * 64);
            kn1 = *(const s8v*)(kptr + jnext * 64 + 32);
            s_phase(ck0, ck1, qf, lp, Pw, li, qd, w2);
            BARRIER_LDS();                               // #2..#32
        }

        // l reduction: qd via shfl, then stash per-wave partials
        #pragma unroll
        for (int it = 0; it < 8; ++it) {
            lp[it] += __shfl_xor(lp[it], 16, 64);
            lp[it] += __shfl_xor(lp[it], 32, 64);
        }
        if (qd == 0) {
            #pragma unroll
            for (int it = 0; it < 8; ++it) l_s[w2 * 128 + it * 16 + li] = lp[it];
        }
        BARRIER_LDS();                                   // #33
        // producers done
    } else {
        // =============== PV-consumer waves (4 waves, c=64 each) ===============
        const int w2c = w - 8;   // 0..3
        f4v acc[4][8];   // [ct][it]: c = c_base+w2c*64+ct*16+qd*4+r, i = i_base+it*16+li
        #pragma unroll
        for (int ct = 0; ct < 4; ++ct)
            #pragma unroll
            for (int it = 0; it < 8; ++it)
                acc[ct][it] = (f4v){0.f, 0.f, 0.f, 0.f};

        const ushort* vptr[4];
        #pragma unroll
        for (int ct = 0; ct < 4; ++ct)
            vptr[ct] = vBb + (size_t)(c_base + w2c * 64 + ct * 16 + li) * N_ + qd * 8;

        // interval 0: prefetch V(0) ch0/1
        s8v vcur[8];                                // [ch*4 + ct], ch=0,1
        #pragma unroll
        for (int ch = 0; ch < 2; ++ch)
            #pragma unroll
            for (int ct = 0; ct < 4; ++ct)
                vcur[ch * 4 + ct] = *(const s8v*)(vptr[ct] + ch * 32);
        BARRIER_LDS();                                   // #1

        #pragma unroll 1
        for (int t = 1; t < N_ / 128; ++t) {
            const ushort* Pr = ((t - 1) & 1) ? Pb1 : Pb0;
            const size_t jprev = (size_t)(t - 1) * 128;
            const size_t jcur  = (size_t)t * 128;

            __builtin_amdgcn_s_setprio(1);               // T5: favor consumer MFMA
            s8v vlt0[4], vlt1[4], vnx[8];
            #pragma unroll
            for (int ct = 0; ct < 4; ++ct)               // V(t-1) ch2
                vlt0[ct] = *(const s8v*)(vptr[ct] + jprev + 2 * 32);
            pv_chunk(Pr, li, qd, 0, &vcur[0], acc);
            #pragma unroll
            for (int ct = 0; ct < 4; ++ct)               // V(t-1) ch3
                vlt1[ct] = *(const s8v*)(vptr[ct] + jprev + 3 * 32);
            pv_chunk(Pr, li, qd, 1, &vcur[4], acc);
            #pragma unroll
            for (int ct = 0; ct < 4; ++ct)               // V(t) ch0 (next interval)
                vnx[ct] = *(const s8v*)(vptr[ct] + jcur);
            pv_chunk(Pr, li, qd, 2, vlt0, acc);
            #pragma unroll
            for (int ct = 0; ct < 4; ++ct)               // V(t) ch1 (next interval)
                vnx[4 + ct] = *(const s8v*)(vptr[ct] + jcur + 32);
            pv_chunk(Pr, li, qd, 3, vlt1, acc);
            __builtin_amdgcn_s_setprio(0);

            #pragma unroll
            for (int k = 0; k < 8; ++k) vcur[k] = vnx[k];
            BARRIER_LDS();                               // #2..#32
        }

        // final PV(T-1)
        {
            const ushort* Pr = ((N_ / 128 - 1) & 1) ? Pb1 : Pb0;
            const size_t jprev = (size_t)(N_ / 128 - 1) * 128;
            s8v vlt0[4], vlt1[4];
            #pragma unroll
            for (int ct = 0; ct < 4; ++ct)
                vlt0[ct] = *(const s8v*)(vptr[ct] + jprev + 2 * 32);
            pv_chunk(Pr, li, qd, 0, &vcur[0], acc);
            #pragma unroll
            for (int ct = 0; ct < 4; ++ct)
                vlt1[ct] = *(const s8v*)(vptr[ct] + jprev + 3 * 32);
            pv_chunk(Pr, li, qd, 1, &vcur[4], acc);
            pv_chunk(Pr, li, qd, 2, vlt0, acc);
            pv_chunk(Pr, li, qd, 3, vlt1, acc);
        }
        BARRIER_LDS();                                   // #33 (l_s ready)

        float inv[8];
        #pragma unroll
        for (int it = 0; it < 8; ++it) {
            float t = 0.f;
            #pragma unroll
            for (int ww = 0; ww < 8; ++ww) t += l_s[ww * 128 + it * 16 + li];
            inv[it] = 1.0f / t;
        }

        // epilogue: out = gamma * acc / l + x
        const float g = gamma[0];
        #pragma unroll
        for (int ct = 0; ct < 4; ++ct)
            #pragma unroll
            for (int it = 0; it < 8; ++it) {
                const int i = i_base + it * 16 + li;
                #pragma unroll
                for (int r = 0; r < 4; ++r) {
                    const int c = c_base + w2c * 64 + ct * 16 + qd * 4 + r;
                    const size_t off = ((size_t)b * C_ + c) * N_ + i;
                    out[off] = g * acc[ct][it][r] * inv[it] + x[off];
                }
            }
    }
}

// ---------------------------------------------------------------------------
extern "C" void kernel_launch(void* const* d_in, const int* in_sizes, int n_in,
                              void* d_out, int out_size, void* d_ws, size_t ws_size,
                              hipStream_t stream)
{
    const float* x     = (const float*)d_in[0];
    const float* Wq    = (const float*)d_in[1];
    const float* bq    = (const float*)d_in[2];
    const float* Wk    = (const float*)d_in[3];
    const float* bk    = (const float*)d_in[4];
    const float* Wv    = (const float*)d_in[5];
    const float* bv    = (const float*)d_in[6];
    const float* gamma = (const float*)d_in[7];
    float* out = (float*)d_out;

    // ws (ushort): vB [B][512][N] | qT [B][N][64] | kT [B][N][64] | Wb [640][512]
    ushort* vB = (ushort*)d_ws;
    ushort* qT = vB + (size_t)B_ * C_ * N_;
    ushort* kT = qT + (size_t)B_ * N_ * 64;
    ushort* Wb = kT + (size_t)B_ * N_ * 64;

    wconv_kernel<<<dim3(640), 256, 0, stream>>>(Wq, Wk, Wv, Wb);
    qkv_fused<<<dim3(N_ / 64, B_), 512, 65536, stream>>>(x, Wb, bq, bk, bv, qT, kT, vB);
    attn_mfma<<<dim3((N_ / 128) * 2 * B_), 768, 69632, stream>>>(qT, kT, vB, x, gamma, out);
}

// Round 9
// 212.303 us; speedup vs baseline: 1.6757x; 1.6757x over previous
//
#include <hip/hip_runtime.h>
#include <math.h>

#define B_ 4
#define C_ 512
#define N_ 4096
#define LOG2E 1.44269504088896f

typedef __attribute__((ext_vector_type(8))) short s8v;   // 8 bf16
typedef __attribute__((ext_vector_type(4))) float f4v;   // MFMA acc

#define MF32(a, b, c) __builtin_amdgcn_mfma_f32_16x16x32_bf16(a, b, c, 0, 0, 0)

#if defined(__has_builtin) && __has_builtin(__builtin_amdgcn_exp2f)
#define EXP2(x) __builtin_amdgcn_exp2f(x)
#else
#define EXP2(x) exp2f(x)
#endif

// Raw barrier: drains LDS ops only (cross-wave P visibility); global-load
// prefetches stay IN FLIGHT across the barrier.
#define BARRIER_LDS() do {                                   \
    __builtin_amdgcn_sched_barrier(0);                       \
    asm volatile("s_waitcnt lgkmcnt(0)" ::: "memory");       \
    __builtin_amdgcn_s_barrier();                            \
    __builtin_amdgcn_sched_barrier(0);                       \
} while (0)

static __device__ __forceinline__ ushort f2bf(float f) {   // RNE
    unsigned u = __float_as_uint(f);
    u += 0x7FFFu + ((u >> 16) & 1u);
    return (ushort)(u >> 16);
}
static __device__ __forceinline__ unsigned pack2bf(float a, float b) {
    unsigned ua = __float_as_uint(a); ua += 0x7FFFu + ((ua >> 16) & 1u);
    unsigned ub = __float_as_uint(b); ub += 0x7FFFu + ((ub >> 16) & 1u);
    return (ua >> 16) | (ub & 0xffff0000u);
}

// ---------------------------------------------------------------------------
// Pass A: Wq|Wk|Wv -> Wb [640][512] bf16
// ---------------------------------------------------------------------------
__global__ __launch_bounds__(256) void wconv_kernel(
    const float* __restrict__ Wq, const float* __restrict__ Wk,
    const float* __restrict__ Wv, ushort* __restrict__ Wb)
{
    const int row = blockIdx.x;
    const float* src = row < 64 ? Wq + (size_t)row * C_
                     : row < 128 ? Wk + (size_t)(row - 64) * C_
                     : Wv + (size_t)(row - 128) * C_;
    const int t2 = threadIdx.x * 2;
    float2 v = *(const float2*)&src[t2];
    ushort2 o; o.x = f2bf(v.x); o.y = f2bf(v.y);
    *(ushort2*)&Wb[(size_t)row * C_ + t2] = o;
}

// ---------------------------------------------------------------------------
// Pass B: fused QKV (unchanged from R4).
// grid (N/64, B) = 256 blocks (1/CU), block 512 (8 waves). Xs [64][512]
// XOR-swizzled, Wb register prefetch 1 k-iter ahead.
// ---------------------------------------------------------------------------
__global__ __launch_bounds__(512, 2) void qkv_fused(
    const float* __restrict__ x, const ushort* __restrict__ Wb,
    const float* __restrict__ bq, const float* __restrict__ bk,
    const float* __restrict__ bv,
    ushort* __restrict__ qT, ushort* __restrict__ kT, ushort* __restrict__ vB)
{
    extern __shared__ ushort Xs[];   // [64][512] bf16, XOR-swizzled, 64 KB

    const int tid = threadIdx.x, w = tid >> 6, lane = tid & 63;
    const int li = lane & 15, qd = lane >> 4;
    const int n0 = blockIdx.x * 64, b = blockIdx.y;

    // ---- stage x[c][n0..n0+63] -> Xs[n][c] bf16 (swizzled) ----
    #pragma unroll
    for (int r = 0; r < 16; ++r) {
        const int f = r * 512 + tid;
        const int c = f >> 4;          // 0..511
        const int nch = f & 15;        // 4-float chunk in n
        float4 v = *(const float4*)&x[((size_t)b * C_ + c) * N_ + n0 + nch * 4];
        const int n = nch * 4;
        Xs[((n + 0) * 512 + c) ^ (((n + 0) & 7) << 3)] = f2bf(v.x);
        Xs[((n + 1) * 512 + c) ^ (((n + 1) & 7) << 3)] = f2bf(v.y);
        Xs[((n + 2) * 512 + c) ^ (((n + 2) & 7) << 3)] = f2bf(v.z);
        Xs[((n + 3) * 512 + c) ^ (((n + 3) & 7) << 3)] = f2bf(v.w);
    }
    __syncthreads();

    const int rb0 = w * 80;
    const ushort* wrow[5];
    #pragma unroll
    for (int ot = 0; ot < 5; ++ot)
        wrow[ot] = Wb + (size_t)(rb0 + ot * 16 + li) * C_ + qd * 8;

    f4v acc[5][4];
    #pragma unroll
    for (int ot = 0; ot < 5; ++ot)
        #pragma unroll
        for (int nt = 0; nt < 4; ++nt)
            acc[ot][nt] = (f4v){0.f, 0.f, 0.f, 0.f};

    // Wb rolling register prefetch (distance 1 k-iter)
    s8v awc[5], awn[5];
    #pragma unroll
    for (int ot = 0; ot < 5; ++ot)
        awc[ot] = *(const s8v*)(wrow[ot]);

    #pragma unroll 1
    for (int kc = 0; kc < C_; kc += 32) {
        const int kn = (kc + 32 < C_) ? kc + 32 : 0;   // last prefetch harmless
        #pragma unroll
        for (int ot = 0; ot < 5; ++ot)
            awn[ot] = *(const s8v*)(wrow[ot] + kn);

        s8v bx[4];
        #pragma unroll
        for (int nt = 0; nt < 4; ++nt) {
            const int n = nt * 16 + li;                // n&7 == li&7
            bx[nt] = *(const s8v*)&Xs[((n * 512) + kc + qd * 8) ^ ((li & 7) << 3)];
        }

        #pragma unroll
        for (int ot = 0; ot < 5; ++ot) {
            if (rb0 + ot * 16 >= 128) {       // v: swapped -> D[m=n][col=o]
                #pragma unroll
                for (int nt = 0; nt < 4; ++nt)
                    acc[ot][nt] = MF32(bx[nt], awc[ot], acc[ot][nt]);
            } else {                           // q/k: D[m=o][col=n]
                #pragma unroll
                for (int nt = 0; nt < 4; ++nt)
                    acc[ot][nt] = MF32(awc[ot], bx[nt], acc[ot][nt]);
            }
        }
        #pragma unroll
        for (int ot = 0; ot < 5; ++ot) awc[ot] = awn[ot];
    }

    #pragma unroll
    for (int ot = 0; ot < 5; ++ot) {
        const int rb = rb0 + ot * 16;
        if (rb < 128) {   // q or k: lane col = n, rows = o (qd*4+r)
            ushort* dst = rb < 64 ? qT : kT;
            const float* bias = rb < 64 ? bq : bk;
            const int ob = (rb < 64 ? rb : rb - 64) + qd * 4;
            const float sc = rb < 64 ? LOG2E : 1.0f;
            #pragma unroll
            for (int nt = 0; nt < 4; ++nt) {
                const int n = n0 + nt * 16 + li;
                ushort4 o;
                o.x = f2bf((acc[ot][nt][0] + bias[ob + 0]) * sc);
                o.y = f2bf((acc[ot][nt][1] + bias[ob + 1]) * sc);
                o.z = f2bf((acc[ot][nt][2] + bias[ob + 2]) * sc);
                o.w = f2bf((acc[ot][nt][3] + bias[ob + 3]) * sc);
                *(ushort4*)&dst[((size_t)b * N_ + n) * 64 + ob] = o;
            }
        } else {          // v: lane col = o (c), rows = n
            const int c = rb - 128 + li;
            const float bb = bv[c];
            #pragma unroll
            for (int nt = 0; nt < 4; ++nt) {
                const int n = n0 + nt * 16 + qd * 4;
                ushort4 o;
                o.x = f2bf(acc[ot][nt][0] + bb);
                o.y = f2bf(acc[ot][nt][1] + bb);
                o.z = f2bf(acc[ot][nt][2] + bb);
                o.w = f2bf(acc[ot][nt][3] + bb);
                *(ushort4*)&vB[((size_t)b * C_ + c) * N_ + n] = o;
            }
        }
    }
}

// ---------------------------------------------------------------------------
// Pass C: MFMA flash attention, producer/consumer waves (R8 resubmit; R7
// retry with register budget fixed: R7 spilled at 12 waves/170-VGPR cap).
// 8 waves = 2/SIMD -> 256 VGPR/wave via launch_bounds(512,2):
//   Waves 0-3 (S-producers, j=32 each): 2 j-subtiles; S = K^T Q, exp2,
//     pack -> Pw, row-sum l. ~120 VGPR.
//   Waves 4-7 (PV-consumers, c=64 each): read Pr once, reuse each pf across
//     4 ct. ~230 VGPR (128 AGPR acc + arch). Fits, no spill.
// Per-CU per-iter work identical to R6 (160 MFMA/SIMD, 80 VMEM) but P LDS
// reads HALVED: 256 -> 128 ds_read_b128 (LDS pipe ~43% of R6's iteration).
// P ping-pong [128][128] XOR-16B-chunk swizzled; l_s [4][128]; LDS 69632 B.
// ---------------------------------------------------------------------------
__device__ __forceinline__ void pv_chunk(
    const ushort* __restrict__ Pr, int li, int qd, int cidx,
    const s8v* vf, f4v (&acc)[4][8])
{
    const int sw = li & 7;             // == row&7 for all rows this lane reads
    #pragma unroll
    for (int h = 0; h < 2; ++h) {          // halves keep pf live-range at 4
        s8v pf[4];
        #pragma unroll
        for (int g = 0; g < 4; ++g)
            pf[g] = *(const s8v*)&Pr[(size_t)((h * 4 + g) * 16 + li) * 128
                                     + (((cidx * 4 + qd) ^ sw) << 3)];
        #pragma unroll
        for (int ct = 0; ct < 4; ++ct)
            #pragma unroll
            for (int g = 0; g < 4; ++g)
                acc[ct][h * 4 + g] = MF32(vf[ct], pf[g], acc[ct][h * 4 + g]);
    }
}

// One 16-wide j-subtile of S for producer waves; chunkbase = 16B-chunk index
// of this subtile's 4-col group for this lane.
__device__ __forceinline__ void s_phase(
    s8v ck0, s8v ck1, const s8v (&qf)[8][2], float (&lp)[8],
    ushort* __restrict__ Pw, int li, int qd, int chunkbase)
{
    const int off = (qd & 1) * 4;          // 8B offset within chunk (shorts)
    const int sw = li & 7;                 // == row&7
    #pragma unroll
    for (int h = 0; h < 2; ++h) {          // halves keep sac live-range at 4
        f4v sac[4];
        #pragma unroll
        for (int g = 0; g < 4; ++g) {
            const int it = h * 4 + g;
            sac[g] = (f4v){0.f, 0.f, 0.f, 0.f};
            sac[g] = MF32(ck0, qf[it][0], sac[g]);
            sac[g] = MF32(ck1, qf[it][1], sac[g]);
        }
        #pragma unroll
        for (int g = 0; g < 4; ++g) {
            const int it = h * 4 + g;
            const float p0 = EXP2(sac[g][0]);
            const float p1 = EXP2(sac[g][1]);
            const float p2 = EXP2(sac[g][2]);
            const float p3 = EXP2(sac[g][3]);
            lp[it] += (p0 + p1) + (p2 + p3);
            uint2 u; u.x = pack2bf(p0, p1); u.y = pack2bf(p2, p3);
            *(uint2*)&Pw[(size_t)(it * 16 + li) * 128
                         + ((chunkbase ^ sw) << 3) + off] = u;
        }
    }
}

__global__ __launch_bounds__(512, 2) void attn_mfma(
    const ushort* __restrict__ qT, const ushort* __restrict__ kT,
    const ushort* __restrict__ vB, const float* __restrict__ x,
    const float* __restrict__ gamma, float* __restrict__ out)
{
    extern __shared__ char smem[];
    ushort* Pb0 = (ushort*)smem;               // [128][128] swizzled
    ushort* Pb1 = (ushort*)(smem + 32768);     // [128][128] swizzled
    float*  l_s = (float*)(smem + 65536);      // [4][128]

    const int tid = threadIdx.x, w = tid >> 6, lane = tid & 63;
    const int li = lane & 15, qd = lane >> 4;
    // XCD grouping (R5): wg -> XCD = wg%8; all 32 i-tiles of one (b, c_half)
    // combo land on one XCD -> V/K/Q L2-resident per XCD (verified: FETCH 3.2x down).
    const int wg = blockIdx.x;
    const int i_base = (wg >> 3) * 128;
    const int combo = wg & 7;
    const int b = combo >> 1;
    const int c_base = (combo & 1) * 256;

    const ushort* qTb = qT + (size_t)b * N_ * 64;
    const ushort* kTb = kT + (size_t)b * N_ * 64;
    const ushort* vBb = vB + (size_t)b * C_ * N_;

    if (w < 4) {
        // =============== S-producer waves (4 waves, j=32 each) ===============
        s8v qf[8][2];
        #pragma unroll
        for (int it = 0; it < 8; ++it)
            #pragma unroll
            for (int ks = 0; ks < 2; ++ks)
                qf[it][ks] = *(const s8v*)&qTb[(size_t)(i_base + it * 16 + li) * 64 + ks * 32 + qd * 8];
        float lp[8] = {0.f, 0.f, 0.f, 0.f, 0.f, 0.f, 0.f, 0.f};

        const ushort* kptrA = kTb + (size_t)(w * 32 + li) * 64 + qd * 8;        // jt=0
        const ushort* kptrB = kTb + (size_t)(w * 32 + 16 + li) * 64 + qd * 8;   // jt=1
        const int cbA = w * 4 + (qd >> 1);        // 16B chunk base, jt=0
        const int cbB = w * 4 + 2 + (qd >> 1);    // jt=1

        // interval 0: K(0) both subtiles, S(0)->Pb0, prefetch K(1)
        s8v ka0 = *(const s8v*)(kptrA);
        s8v ka1 = *(const s8v*)(kptrA + 32);
        s8v kb0 = *(const s8v*)(kptrB);
        s8v kb1 = *(const s8v*)(kptrB + 32);
        s8v na0 = *(const s8v*)(kptrA + (size_t)128 * 64);
        s8v na1 = *(const s8v*)(kptrA + (size_t)128 * 64 + 32);
        s8v nb0 = *(const s8v*)(kptrB + (size_t)128 * 64);
        s8v nb1 = *(const s8v*)(kptrB + (size_t)128 * 64 + 32);
        s_phase(ka0, ka1, qf, lp, Pb0, li, qd, cbA);
        s_phase(kb0, kb1, qf, lp, Pb0, li, qd, cbB);
        BARRIER_LDS();                                   // #1

        #pragma unroll 1
        for (int t = 1; t < N_ / 128; ++t) {
            ushort* Pw = ((t - 1) & 1) ? Pb0 : Pb1;
            const size_t jnext = (t + 1 < N_ / 128) ? (size_t)(t + 1) * 128 : 0;
            s8v ca0 = na0, ca1 = na1, cb0 = nb0, cb1 = nb1;
            na0 = *(const s8v*)(kptrA + jnext * 64);
            na1 = *(const s8v*)(kptrA + jnext * 64 + 32);
            nb0 = *(const s8v*)(kptrB + jnext * 64);
            nb1 = *(const s8v*)(kptrB + jnext * 64 + 32);
            s_phase(ca0, ca1, qf, lp, Pw, li, qd, cbA);
            s_phase(cb0, cb1, qf, lp, Pw, li, qd, cbB);
            BARRIER_LDS();                               // #2..#32
        }

        // l reduction: qd via shfl, then stash per-wave partials
        #pragma unroll
        for (int it = 0; it < 8; ++it) {
            lp[it] += __shfl_xor(lp[it], 16, 64);
            lp[it] += __shfl_xor(lp[it], 32, 64);
        }
        if (qd == 0) {
            #pragma unroll
            for (int it = 0; it < 8; ++it) l_s[w * 128 + it * 16 + li] = lp[it];
        }
        BARRIER_LDS();                                   // #33
        // producers done
    } else {
        // =============== PV-consumer waves (4 waves, c=64 each) ===============
        const int w2c = w - 4;   // 0..3
        f4v acc[4][8];   // [ct][it]: c = c_base+w2c*64+ct*16+qd*4+r, i = i_base+it*16+li
        #pragma unroll
        for (int ct = 0; ct < 4; ++ct)
            #pragma unroll
            for (int it = 0; it < 8; ++it)
                acc[ct][it] = (f4v){0.f, 0.f, 0.f, 0.f};

        const ushort* vptr[4];
        #pragma unroll
        for (int ct = 0; ct < 4; ++ct)
            vptr[ct] = vBb + (size_t)(c_base + w2c * 64 + ct * 16 + li) * N_ + qd * 8;

        // interval 0: prefetch V(0) ch0/1
        s8v vcur[8];                                // [ch*4 + ct], ch=0,1
        #pragma unroll
        for (int ch = 0; ch < 2; ++ch)
            #pragma unroll
            for (int ct = 0; ct < 4; ++ct)
                vcur[ch * 4 + ct] = *(const s8v*)(vptr[ct] + ch * 32);
        BARRIER_LDS();                                   // #1

        #pragma unroll 1
        for (int t = 1; t < N_ / 128; ++t) {
            const ushort* Pr = ((t - 1) & 1) ? Pb1 : Pb0;
            const size_t jprev = (size_t)(t - 1) * 128;
            const size_t jcur  = (size_t)t * 128;

            __builtin_amdgcn_s_setprio(1);               // T5: favor consumer MFMA
            s8v vlt0[4], vlt1[4], vnx[8];
            #pragma unroll
            for (int ct = 0; ct < 4; ++ct)               // V(t-1) ch2
                vlt0[ct] = *(const s8v*)(vptr[ct] + jprev + 2 * 32);
            pv_chunk(Pr, li, qd, 0, &vcur[0], acc);
            #pragma unroll
            for (int ct = 0; ct < 4; ++ct)               // V(t-1) ch3
                vlt1[ct] = *(const s8v*)(vptr[ct] + jprev + 3 * 32);
            pv_chunk(Pr, li, qd, 1, &vcur[4], acc);
            #pragma unroll
            for (int ct = 0; ct < 4; ++ct)               // V(t) ch0 (next interval)
                vnx[ct] = *(const s8v*)(vptr[ct] + jcur);
            pv_chunk(Pr, li, qd, 2, vlt0, acc);
            #pragma unroll
            for (int ct = 0; ct < 4; ++ct)               // V(t) ch1 (next interval)
                vnx[4 + ct] = *(const s8v*)(vptr[ct] + jcur + 32);
            pv_chunk(Pr, li, qd, 3, vlt1, acc);
            __builtin_amdgcn_s_setprio(0);

            #pragma unroll
            for (int k = 0; k < 8; ++k) vcur[k] = vnx[k];
            BARRIER_LDS();                               // #2..#32
        }

        // final PV(T-1)
        {
            const ushort* Pr = ((N_ / 128 - 1) & 1) ? Pb1 : Pb0;
            const size_t jprev = (size_t)(N_ / 128 - 1) * 128;
            s8v vlt0[4], vlt1[4];
            #pragma unroll
            for (int ct = 0; ct < 4; ++ct)
                vlt0[ct] = *(const s8v*)(vptr[ct] + jprev + 2 * 32);
            pv_chunk(Pr, li, qd, 0, &vcur[0], acc);
            #pragma unroll
            for (int ct = 0; ct < 4; ++ct)
                vlt1[ct] = *(const s8v*)(vptr[ct] + jprev + 3 * 32);
            pv_chunk(Pr, li, qd, 1, &vcur[4], acc);
            pv_chunk(Pr, li, qd, 2, vlt0, acc);
            pv_chunk(Pr, li, qd, 3, vlt1, acc);
        }
        BARRIER_LDS();                                   // #33 (l_s ready)

        float inv[8];
        #pragma unroll
        for (int it = 0; it < 8; ++it) {
            float t = 0.f;
            #pragma unroll
            for (int ww = 0; ww < 4; ++ww) t += l_s[ww * 128 + it * 16 + li];
            inv[it] = 1.0f / t;
        }

        // epilogue: out = gamma * acc / l + x
        const float g = gamma[0];
        #pragma unroll
        for (int ct = 0; ct < 4; ++ct)
            #pragma unroll
            for (int it = 0; it < 8; ++it) {
                const int i = i_base + it * 16 + li;
                #pragma unroll
                for (int r = 0; r < 4; ++r) {
                    const int c = c_base + w2c * 64 + ct * 16 + qd * 4 + r;
                    const size_t off = ((size_t)b * C_ + c) * N_ + i;
                    out[off] = g * acc[ct][it][r] * inv[it] + x[off];
                }
            }
    }
}

// ---------------------------------------------------------------------------
extern "C" void kernel_launch(void* const* d_in, const int* in_sizes, int n_in,
                              void* d_out, int out_size, void* d_ws, size_t ws_size,
                              hipStream_t stream)
{
    const float* x     = (const float*)d_in[0];
    const float* Wq    = (const float*)d_in[1];
    const float* bq    = (const float*)d_in[2];
    const float* Wk    = (const float*)d_in[3];
    const float* bk    = (const float*)d_in[4];
    const float* Wv    = (const float*)d_in[5];
    const float* bv    = (const float*)d_in[6];
    const float* gamma = (const float*)d_in[7];
    float* out = (float*)d_out;

    // ws (ushort): vB [B][512][N] | qT [B][N][64] | kT [B][N][64] | Wb [640][512]
    ushort* vB = (ushort*)d_ws;
    ushort* qT = vB + (size_t)B_ * C_ * N_;
    ushort* kT = qT + (size_t)B_ * N_ * 64;
    ushort* Wb = kT + (size_t)B_ * N_ * 64;

    wconv_kernel<<<dim3(640), 256, 0, stream>>>(Wq, Wk, Wv, Wb);
    qkv_fused<<<dim3(N_ / 64, B_), 512, 65536, stream>>>(x, Wb, bq, bk, bv, qT, kT, vB);
    attn_mfma<<<dim3((N_ / 128) * 2 * B_), 512, 69632, stream>>>(qT, kT, vB, x, gamma, out);
}

// Round 10
// 205.355 us; speedup vs baseline: 1.7323x; 1.0338x over previous
//
#include <hip/hip_runtime.h>
#include <math.h>

#define B_ 4
#define C_ 512
#define N_ 4096
#define LOG2E 1.44269504088896f

typedef __attribute__((ext_vector_type(8))) short s8v;   // 8 bf16
typedef __attribute__((ext_vector_type(4))) float f4v;   // MFMA acc

#define MF32(a, b, c) __builtin_amdgcn_mfma_f32_16x16x32_bf16(a, b, c, 0, 0, 0)

#if defined(__has_builtin) && __has_builtin(__builtin_amdgcn_exp2f)
#define EXP2(x) __builtin_amdgcn_exp2f(x)
#else
#define EXP2(x) exp2f(x)
#endif

// Raw barrier: drains LDS ops only (cross-wave P visibility); global-load
// prefetches stay IN FLIGHT across the barrier.
#define BARRIER_LDS() do {                                   \
    __builtin_amdgcn_sched_barrier(0);                       \
    asm volatile("s_waitcnt lgkmcnt(0)" ::: "memory");       \
    __builtin_amdgcn_s_barrier();                            \
    __builtin_amdgcn_sched_barrier(0);                       \
} while (0)

static __device__ __forceinline__ ushort f2bf(float f) {   // RNE
    unsigned u = __float_as_uint(f);
    u += 0x7FFFu + ((u >> 16) & 1u);
    return (ushort)(u >> 16);
}
static __device__ __forceinline__ unsigned pack2bf(float a, float b) {
    unsigned ua = __float_as_uint(a); ua += 0x7FFFu + ((ua >> 16) & 1u);
    unsigned ub = __float_as_uint(b); ub += 0x7FFFu + ((ub >> 16) & 1u);
    return (ua >> 16) | (ub & 0xffff0000u);
}

// ---------------------------------------------------------------------------
// Pass A: Wq|Wk|Wv -> Wb [640][512] bf16
// ---------------------------------------------------------------------------
__global__ __launch_bounds__(256) void wconv_kernel(
    const float* __restrict__ Wq, const float* __restrict__ Wk,
    const float* __restrict__ Wv, ushort* __restrict__ Wb)
{
    const int row = blockIdx.x;
    const float* src = row < 64 ? Wq + (size_t)row * C_
                     : row < 128 ? Wk + (size_t)(row - 64) * C_
                     : Wv + (size_t)(row - 128) * C_;
    const int t2 = threadIdx.x * 2;
    float2 v = *(const float2*)&src[t2];
    ushort2 o; o.x = f2bf(v.x); o.y = f2bf(v.y);
    *(ushort2*)&Wb[(size_t)row * C_ + t2] = o;
}

// ---------------------------------------------------------------------------
// Pass B: fused QKV (unchanged from R4).
// grid (N/64, B) = 256 blocks (1/CU), block 512 (8 waves). Xs [64][512]
// XOR-swizzled, Wb register prefetch 1 k-iter ahead.
// ---------------------------------------------------------------------------
__global__ __launch_bounds__(512, 2) void qkv_fused(
    const float* __restrict__ x, const ushort* __restrict__ Wb,
    const float* __restrict__ bq, const float* __restrict__ bk,
    const float* __restrict__ bv,
    ushort* __restrict__ qT, ushort* __restrict__ kT, ushort* __restrict__ vB)
{
    extern __shared__ ushort Xs[];   // [64][512] bf16, XOR-swizzled, 64 KB

    const int tid = threadIdx.x, w = tid >> 6, lane = tid & 63;
    const int li = lane & 15, qd = lane >> 4;
    const int n0 = blockIdx.x * 64, b = blockIdx.y;

    // ---- stage x[c][n0..n0+63] -> Xs[n][c] bf16 (swizzled) ----
    #pragma unroll
    for (int r = 0; r < 16; ++r) {
        const int f = r * 512 + tid;
        const int c = f >> 4;          // 0..511
        const int nch = f & 15;        // 4-float chunk in n
        float4 v = *(const float4*)&x[((size_t)b * C_ + c) * N_ + n0 + nch * 4];
        const int n = nch * 4;
        Xs[((n + 0) * 512 + c) ^ (((n + 0) & 7) << 3)] = f2bf(v.x);
        Xs[((n + 1) * 512 + c) ^ (((n + 1) & 7) << 3)] = f2bf(v.y);
        Xs[((n + 2) * 512 + c) ^ (((n + 2) & 7) << 3)] = f2bf(v.z);
        Xs[((n + 3) * 512 + c) ^ (((n + 3) & 7) << 3)] = f2bf(v.w);
    }
    __syncthreads();

    const int rb0 = w * 80;
    const ushort* wrow[5];
    #pragma unroll
    for (int ot = 0; ot < 5; ++ot)
        wrow[ot] = Wb + (size_t)(rb0 + ot * 16 + li) * C_ + qd * 8;

    f4v acc[5][4];
    #pragma unroll
    for (int ot = 0; ot < 5; ++ot)
        #pragma unroll
        for (int nt = 0; nt < 4; ++nt)
            acc[ot][nt] = (f4v){0.f, 0.f, 0.f, 0.f};

    // Wb rolling register prefetch (distance 1 k-iter)
    s8v awc[5], awn[5];
    #pragma unroll
    for (int ot = 0; ot < 5; ++ot)
        awc[ot] = *(const s8v*)(wrow[ot]);

    #pragma unroll 1
    for (int kc = 0; kc < C_; kc += 32) {
        const int kn = (kc + 32 < C_) ? kc + 32 : 0;   // last prefetch harmless
        #pragma unroll
        for (int ot = 0; ot < 5; ++ot)
            awn[ot] = *(const s8v*)(wrow[ot] + kn);

        s8v bx[4];
        #pragma unroll
        for (int nt = 0; nt < 4; ++nt) {
            const int n = nt * 16 + li;                // n&7 == li&7
            bx[nt] = *(const s8v*)&Xs[((n * 512) + kc + qd * 8) ^ ((li & 7) << 3)];
        }

        #pragma unroll
        for (int ot = 0; ot < 5; ++ot) {
            if (rb0 + ot * 16 >= 128) {       // v: swapped -> D[m=n][col=o]
                #pragma unroll
                for (int nt = 0; nt < 4; ++nt)
                    acc[ot][nt] = MF32(bx[nt], awc[ot], acc[ot][nt]);
            } else {                           // q/k: D[m=o][col=n]
                #pragma unroll
                for (int nt = 0; nt < 4; ++nt)
                    acc[ot][nt] = MF32(awc[ot], bx[nt], acc[ot][nt]);
            }
        }
        #pragma unroll
        for (int ot = 0; ot < 5; ++ot) awc[ot] = awn[ot];
    }

    #pragma unroll
    for (int ot = 0; ot < 5; ++ot) {
        const int rb = rb0 + ot * 16;
        if (rb < 128) {   // q or k: lane col = n, rows = o (qd*4+r)
            ushort* dst = rb < 64 ? qT : kT;
            const float* bias = rb < 64 ? bq : bk;
            const int ob = (rb < 64 ? rb : rb - 64) + qd * 4;
            const float sc = rb < 64 ? LOG2E : 1.0f;
            #pragma unroll
            for (int nt = 0; nt < 4; ++nt) {
                const int n = n0 + nt * 16 + li;
                ushort4 o;
                o.x = f2bf((acc[ot][nt][0] + bias[ob + 0]) * sc);
                o.y = f2bf((acc[ot][nt][1] + bias[ob + 1]) * sc);
                o.z = f2bf((acc[ot][nt][2] + bias[ob + 2]) * sc);
                o.w = f2bf((acc[ot][nt][3] + bias[ob + 3]) * sc);
                *(ushort4*)&dst[((size_t)b * N_ + n) * 64 + ob] = o;
            }
        } else {          // v: lane col = o (c), rows = n
            const int c = rb - 128 + li;
            const float bb = bv[c];
            #pragma unroll
            for (int nt = 0; nt < 4; ++nt) {
                const int n = n0 + nt * 16 + qd * 4;
                ushort4 o;
                o.x = f2bf(acc[ot][nt][0] + bb);
                o.y = f2bf(acc[ot][nt][1] + bb);
                o.z = f2bf(acc[ot][nt][2] + bb);
                o.w = f2bf(acc[ot][nt][3] + bb);
                *(ushort4*)&vB[((size_t)b * C_ + c) * N_ + n] = o;
            }
        }
    }
}

// ---------------------------------------------------------------------------
// Pass C: MFMA flash attention, producer/consumer waves (R10).
// R9 structure (8 waves = 2/SIMD, 4 S-producers j=64 each now, 4 PV-consumers
// c=64 each) with TWO changes targeting the ~4000 cyc/iter barrier-coupled
// stall (pipes only account for ~4000 of 8040 cyc/iter):
// 1. j-iteration 128 -> 256: P ping-pong [128][256] (2 x 64 KB, LDS =
//    131072 B exactly - proven size). 17 barriers instead of 33 -> skew
//    penalty paid half as often. l_s ALIASES Pb0 (dead after last consumer
//    read of Pb0 at barrier #16; producers write it between #16 and #17).
// 2. V cover depth 2 chunks: ring vr[2], load chunk c+2 after computing
//    chunk c (~300 cyc cover vs ~200 cyc L2 latency; loads cross barriers).
// XCD pinning (combo = wg&7) and P XOR-16B-chunk swizzle kept.
// ---------------------------------------------------------------------------
__device__ __forceinline__ void pv_chunk(
    const ushort* __restrict__ Pr, int li, int qd, int cidx,
    const s8v* vf, f4v (&acc)[4][8])
{
    const int sw = li & 7;             // == row&7 for all rows this lane reads
    #pragma unroll
    for (int h = 0; h < 2; ++h) {          // halves keep pf live-range at 4
        s8v pf[4];
        #pragma unroll
        for (int g = 0; g < 4; ++g)
            pf[g] = *(const s8v*)&Pr[(size_t)((h * 4 + g) * 16 + li) * 256
                                     + (((cidx * 4 + qd) ^ sw) << 3)];
        #pragma unroll
        for (int ct = 0; ct < 4; ++ct)
            #pragma unroll
            for (int g = 0; g < 4; ++g)
                acc[ct][h * 4 + g] = MF32(vf[ct], pf[g], acc[ct][h * 4 + g]);
    }
}

// One 16-wide j-subtile of S; chunkbase = 16B-chunk index (0..31) of this
// subtile's 4-col group for this lane.
__device__ __forceinline__ void s_phase(
    s8v ck0, s8v ck1, const s8v (&qf)[8][2], float (&lp)[8],
    ushort* __restrict__ Pw, int li, int qd, int chunkbase)
{
    const int off = (qd & 1) * 4;          // 8B offset within chunk (shorts)
    const int sw = li & 7;                 // == row&7
    #pragma unroll
    for (int h = 0; h < 2; ++h) {          // halves keep sac live-range at 4
        f4v sac[4];
        #pragma unroll
        for (int g = 0; g < 4; ++g) {
            const int it = h * 4 + g;
            sac[g] = (f4v){0.f, 0.f, 0.f, 0.f};
            sac[g] = MF32(ck0, qf[it][0], sac[g]);
            sac[g] = MF32(ck1, qf[it][1], sac[g]);
        }
        #pragma unroll
        for (int g = 0; g < 4; ++g) {
            const int it = h * 4 + g;
            const float p0 = EXP2(sac[g][0]);
            const float p1 = EXP2(sac[g][1]);
            const float p2 = EXP2(sac[g][2]);
            const float p3 = EXP2(sac[g][3]);
            lp[it] += (p0 + p1) + (p2 + p3);
            uint2 u; u.x = pack2bf(p0, p1); u.y = pack2bf(p2, p3);
            *(uint2*)&Pw[(size_t)(it * 16 + li) * 256
                         + ((chunkbase ^ sw) << 3) + off] = u;
        }
    }
}

__global__ __launch_bounds__(512, 2) void attn_mfma(
    const ushort* __restrict__ qT, const ushort* __restrict__ kT,
    const ushort* __restrict__ vB, const float* __restrict__ x,
    const float* __restrict__ gamma, float* __restrict__ out)
{
    extern __shared__ char smem[];
    ushort* Pb0 = (ushort*)smem;               // [128][256] swizzled, 64 KB
    ushort* Pb1 = (ushort*)(smem + 65536);     // [128][256] swizzled, 64 KB
    float*  l_s = (float*)smem;                // [4][128] ALIASES Pb0 (dead)

    const int tid = threadIdx.x, w = tid >> 6, lane = tid & 63;
    const int li = lane & 15, qd = lane >> 4;
    // XCD grouping (R5): wg -> XCD = wg%8; all 32 i-tiles of one (b, c_half)
    // combo land on one XCD -> V/K/Q L2-resident per XCD.
    const int wg = blockIdx.x;
    const int i_base = (wg >> 3) * 128;
    const int combo = wg & 7;
    const int b = combo >> 1;
    const int c_base = (combo & 1) * 256;

    const ushort* qTb = qT + (size_t)b * N_ * 64;
    const ushort* kTb = kT + (size_t)b * N_ * 64;
    const ushort* vBb = vB + (size_t)b * C_ * N_;

    const int NT = N_ / 256;   // 16 j-iterations of 256

    if (w < 4) {
        // ========== S-producer waves (4 waves, j=64 each: 4 subtiles) =======
        s8v qf[8][2];
        #pragma unroll
        for (int it = 0; it < 8; ++it)
            #pragma unroll
            for (int ks = 0; ks < 2; ++ks)
                qf[it][ks] = *(const s8v*)&qTb[(size_t)(i_base + it * 16 + li) * 64 + ks * 32 + qd * 8];
        float lp[8] = {0.f, 0.f, 0.f, 0.f, 0.f, 0.f, 0.f, 0.f};

        const ushort* kp[4];
        int cb[4];
        #pragma unroll
        for (int s = 0; s < 4; ++s) {
            kp[s] = kTb + (size_t)(w * 64 + s * 16 + li) * 64 + qd * 8;
            cb[s] = w * 8 + s * 2 + (qd >> 1);
        }

        // interval 0: K(0) all 4 subtiles -> S(0)->Pb0; prefetch K(1)
        s8v kn0[4], kn1[4];
        {
            s8v kc0[4], kc1[4];
            #pragma unroll
            for (int s = 0; s < 4; ++s) {
                kc0[s] = *(const s8v*)(kp[s]);
                kc1[s] = *(const s8v*)(kp[s] + 32);
            }
            #pragma unroll
            for (int s = 0; s < 4; ++s) {
                kn0[s] = *(const s8v*)(kp[s] + (size_t)256 * 64);
                kn1[s] = *(const s8v*)(kp[s] + (size_t)256 * 64 + 32);
            }
            #pragma unroll
            for (int s = 0; s < 4; ++s)
                s_phase(kc0[s], kc1[s], qf, lp, Pb0, li, qd, cb[s]);
        }
        BARRIER_LDS();                                   // #1

        #pragma unroll 1
        for (int t = 1; t < NT; ++t) {
            ushort* Pw = ((t - 1) & 1) ? Pb0 : Pb1;
            const size_t jnext = (t + 1 < NT) ? (size_t)(t + 1) * 256 : 0;
            #pragma unroll
            for (int s = 0; s < 4; ++s) {
                s8v c0 = kn0[s], c1 = kn1[s];
                kn0[s] = *(const s8v*)(kp[s] + jnext * 64);
                kn1[s] = *(const s8v*)(kp[s] + jnext * 64 + 32);
                s_phase(c0, c1, qf, lp, Pw, li, qd, cb[s]);
            }
            BARRIER_LDS();                               // #2..#16
        }

        // l reduction: qd via shfl; write partials into l_s (aliases Pb0 —
        // consumers' last Pb0 read completed before barrier #16).
        #pragma unroll
        for (int it = 0; it < 8; ++it) {
            lp[it] += __shfl_xor(lp[it], 16, 64);
            lp[it] += __shfl_xor(lp[it], 32, 64);
        }
        if (qd == 0) {
            #pragma unroll
            for (int it = 0; it < 8; ++it) l_s[w * 128 + it * 16 + li] = lp[it];
        }
        BARRIER_LDS();                                   // #17
        // producers done
    } else {
        // ========== PV-consumer waves (4 waves, c=64 each) ==================
        const int w2c = w - 4;   // 0..3
        f4v acc[4][8];   // [ct][it]: c = c_base+w2c*64+ct*16+qd*4+r, i = i_base+it*16+li
        #pragma unroll
        for (int ct = 0; ct < 4; ++ct)
            #pragma unroll
            for (int it = 0; it < 8; ++it)
                acc[ct][it] = (f4v){0.f, 0.f, 0.f, 0.f};

        const ushort* vptr[4];
        #pragma unroll
        for (int ct = 0; ct < 4; ++ct)
            vptr[ct] = vBb + (size_t)(c_base + w2c * 64 + ct * 16 + li) * N_ + qd * 8;

        // interval 0: prefetch V chunks 0,1 of j-tile 0 into ring vr[0],vr[1]
        s8v vr[2][4];
        #pragma unroll
        for (int sl = 0; sl < 2; ++sl)
            #pragma unroll
            for (int ct = 0; ct < 4; ++ct)
                vr[sl][ct] = *(const s8v*)(vptr[ct] + sl * 32);
        BARRIER_LDS();                                   // #1

        #pragma unroll 1
        for (int t = 1; t < NT; ++t) {
            const ushort* Pr = ((t - 1) & 1) ? Pb1 : Pb0;
            const size_t jprev = (size_t)(t - 1) * 256;
            const size_t jcur  = (size_t)t * 256;

            __builtin_amdgcn_s_setprio(1);
            #pragma unroll
            for (int c = 0; c < 8; ++c) {
                pv_chunk(Pr, li, qd, c, vr[c & 1], acc);
                // reload slot c&1 with chunk c+2 (this tile) or wrap to next
                const size_t jld = (c + 2 < 8) ? jprev + (size_t)(c + 2) * 32
                                               : jcur + (size_t)(c + 2 - 8) * 32;
                #pragma unroll
                for (int ct = 0; ct < 4; ++ct)
                    vr[c & 1][ct] = *(const s8v*)(vptr[ct] + jld);
            }
            __builtin_amdgcn_s_setprio(0);
            BARRIER_LDS();                               // #2..#16
        }

        // final PV (tile NT-1): Pr = Pb1 (since (NT-2)&1 == 0 -> producers
        // wrote S(NT-1) into Pb1); no further prefetch.
        {
            const ushort* Pr = ((NT - 2) & 1) ? Pb0 : Pb1;
            const size_t jprev = (size_t)(NT - 1) * 256;
            __builtin_amdgcn_s_setprio(1);
            #pragma unroll
            for (int c = 0; c < 8; ++c) {
                pv_chunk(Pr, li, qd, c, vr[c & 1], acc);
                if (c + 2 < 8) {
                    const size_t jld = jprev + (size_t)(c + 2) * 32;
                    #pragma unroll
                    for (int ct = 0; ct < 4; ++ct)
                        vr[c & 1][ct] = *(const s8v*)(vptr[ct] + jld);
                }
            }
            __builtin_amdgcn_s_setprio(0);
        }
        BARRIER_LDS();                                   // #17 (l_s ready)

        float inv[8];
        #pragma unroll
        for (int it = 0; it < 8; ++it) {
            float t = 0.f;
            #pragma unroll
            for (int ww = 0; ww < 4; ++ww) t += l_s[ww * 128 + it * 16 + li];
            inv[it] = 1.0f / t;
        }

        // epilogue: out = gamma * acc / l + x
        const float g = gamma[0];
        #pragma unroll
        for (int ct = 0; ct < 4; ++ct)
            #pragma unroll
            for (int it = 0; it < 8; ++it) {
                const int i = i_base + it * 16 + li;
                #pragma unroll
                for (int r = 0; r < 4; ++r) {
                    const int c = c_base + w2c * 64 + ct * 16 + qd * 4 + r;
                    const size_t off = ((size_t)b * C_ + c) * N_ + i;
                    out[off] = g * acc[ct][it][r] * inv[it] + x[off];
                }
            }
    }
}

// ---------------------------------------------------------------------------
extern "C" void kernel_launch(void* const* d_in, const int* in_sizes, int n_in,
                              void* d_out, int out_size, void* d_ws, size_t ws_size,
                              hipStream_t stream)
{
    const float* x     = (const float*)d_in[0];
    const float* Wq    = (const float*)d_in[1];
    const float* bq    = (const float*)d_in[2];
    const float* Wk    = (const float*)d_in[3];
    const float* bk    = (const float*)d_in[4];
    const float* Wv    = (const float*)d_in[5];
    const float* bv    = (const float*)d_in[6];
    const float* gamma = (const float*)d_in[7];
    float* out = (float*)d_out;

    // ws (ushort): vB [B][512][N] | qT [B][N][64] | kT [B][N][64] | Wb [640][512]
    ushort* vB = (ushort*)d_ws;
    ushort* qT = vB + (size_t)B_ * C_ * N_;
    ushort* kT = qT + (size_t)B_ * N_ * 64;
    ushort* Wb = kT + (size_t)B_ * N_ * 64;

    wconv_kernel<<<dim3(640), 256, 0, stream>>>(Wq, Wk, Wv, Wb);
    qkv_fused<<<dim3(N_ / 64, B_), 512, 65536, stream>>>(x, Wb, bq, bk, bv, qT, kT, vB);
    attn_mfma<<<dim3((N_ / 128) * 2 * B_), 512, 131072, stream>>>(qT, kT, vB, x, gamma, out);
}